// Round 5
// baseline (55.290 us; speedup 1.0000x reference)
//
#include <hip/hip_runtime.h>
#include <math.h>

#define U 128

typedef __attribute__((ext_vector_type(8))) short bf16x8;
typedef __attribute__((ext_vector_type(4))) float f32x4;

__device__ inline unsigned int pack2(float a, float b) {
    // low short = bf16(a) (truncated), high short = bf16(b)
    return (__float_as_uint(a) >> 16) | (__float_as_uint(b) & 0xFFFF0000u);
}
__device__ inline float lo_of(float a) {
    return a - __uint_as_float(__float_as_uint(a) & 0xFFFF0000u);
}
__device__ inline float fromhi(unsigned short h) {
    return __uint_as_float(((unsigned int)h) << 16);
}
__device__ inline float tanh_fast(float v) {
    float e = __expf(2.0f * v);
    return 1.0f - 2.0f / (e + 1.0f);
}
#define MFMA(A, B, C) __builtin_amdgcn_mfma_f32_16x16x32_bf16(A, B, C, 0, 0, 0)

// ---------------------------------------------------------------------------
// k_split: elementwise f32 -> (trunc-bf16 hi, bf16 lo) for X, Wi, Wb.
// ---------------------------------------------------------------------------
__global__ __launch_bounds__(256) void k_split(
        const float* __restrict__ X, const float* __restrict__ Wi,
        const float* __restrict__ Wb,
        unsigned short* __restrict__ Xh, unsigned short* __restrict__ Xl,
        unsigned short* __restrict__ Wih, unsigned short* __restrict__ Wil,
        unsigned short* __restrict__ Wbh, unsigned short* __restrict__ Wbl,
        int n4X, int n4Wi, int n4Wb) {
    int i = blockIdx.x * blockDim.x + threadIdx.x;
    const float* src;
    unsigned short *dh, *dl;
    int j;
    if (i < n4X)                    { j = i;               src = X;  dh = Xh;  dl = Xl;  }
    else if (i < n4X + n4Wi)        { j = i - n4X;         src = Wi; dh = Wih; dl = Wil; }
    else if (i < n4X + n4Wi + n4Wb) { j = i - n4X - n4Wi;  src = Wb; dh = Wbh; dl = Wbl; }
    else return;
    float4 v = *(const float4*)&src[(long)j * 4];
    uint2 hh, ll;
    hh.x = pack2(v.x, v.y);               hh.y = pack2(v.z, v.w);
    ll.x = pack2(lo_of(v.x), lo_of(v.y)); ll.y = pack2(lo_of(v.z), lo_of(v.w));
    *(uint2*)&dh[(long)j * 4] = hh;
    *(uint2*)&dl[(long)j * 4] = ll;
}

// ---------------------------------------------------------------------------
// k_all: fully fused network, SWAPPED-operand MFMA form.
// grid = B/16, 512 threads (8 waves). Block owns 16 batch rows; wave w owns
// cols 16w..16w+15.
//
// Swapped MFMA: D = A·B with A = W-frag (m = output col c), B = z^T-frag
// (n = batch row r). C/D layout => lane l15 = batch row, reg i = col
// 16w+4lq+i: z_new is ROW-MAJOR PER LANE -> one ds_write_b64 (hi) + one (lo).
// LDS z layout: byte(r,c) = r*256 + ((2c) ^ ((r&7)<<4))  (XOR swizzle; reads
// ds_read_b128 16B-aligned, writes ds_write_b64 8B-aligned, <=2 lanes/bank).
//
// Convergence: dmax measured only at it%4==3, consensus consumed at it%4==0
// (one iter late, LDS read overlapped with z-frag reads). Cap 48, tol 1e-5.
// ---------------------------------------------------------------------------
__global__ __launch_bounds__(512) void k_all(
        const unsigned short* __restrict__ Xh, const unsigned short* __restrict__ Xl,
        const unsigned short* __restrict__ Wih, const unsigned short* __restrict__ Wil,
        const unsigned short* __restrict__ Wbh, const unsigned short* __restrict__ Wbl,
        const float* __restrict__ bi,
        const float* __restrict__ Wo, const float* __restrict__ bo,
        float* __restrict__ Out, int L) {
    __shared__ unsigned short zhS[2][16 * U];   // 8 KB hi (double-buffered)
    __shared__ unsigned short zlS[2][16 * U];   // 8 KB lo
    __shared__ float red[8];

    const int tid  = threadIdx.x;
    const int w    = tid >> 6;
    const int lane = tid & 63;
    const int l15  = lane & 15;
    const int lq   = lane >> 4;
    const int r0   = blockIdx.x * 16;
    const int colA = w * 16 + l15;     // W row for A-frags (= output col)
    const int KD   = 784;

    // ---------------- Phase 1: x = X @ Wi^T + bi (swapped) ----------------
    float4 bi4 = *(const float4*)&bi[w * 16 + lq * 4];
    f32x4 a0 = {bi4.x, bi4.y, bi4.z, bi4.w};
    f32x4 a1 = {0.f, 0.f, 0.f, 0.f};
    f32x4 a2 = {0.f, 0.f, 0.f, 0.f};
    {
        const unsigned short* xhp = &Xh[(long)(r0 + l15) * KD];
        const unsigned short* xlp = &Xl[(long)(r0 + l15) * KD];
        const unsigned short* whp = &Wih[(long)colA * KD];
        const unsigned short* wlp = &Wil[(long)colA * KD];
        #pragma unroll 4
        for (int kc = 0; kc < 24; ++kc) {
            const int k = kc * 32 + lq * 8;
            bf16x8 ah = *(const bf16x8*)&xhp[k];
            bf16x8 al = *(const bf16x8*)&xlp[k];
            bf16x8 bh = *(const bf16x8*)&whp[k];
            bf16x8 bl = *(const bf16x8*)&wlp[k];
            a0 = MFMA(bh, ah, a0);     // Wh . xh
            a1 = MFMA(bh, al, a1);     // Wh . xl
            a2 = MFMA(bl, ah, a2);     // Wl . xh
        }
        bf16x8 ah = {0,0,0,0,0,0,0,0}, al = ah, bh = ah, bl = ah;
        if (lq < 2) {
            const int k = 768 + lq * 8;
            ah = *(const bf16x8*)&xhp[k];
            al = *(const bf16x8*)&xlp[k];
            bh = *(const bf16x8*)&whp[k];
            bl = *(const bf16x8*)&wlp[k];
        }
        a0 = MFMA(bh, ah, a0);
        a1 = MFMA(bh, al, a1);
        a2 = MFMA(bl, ah, a2);
    }
    // lane l15 = batch row, reg i = col 16w+4lq+i
    float xf[4], zr[4];
    #pragma unroll
    for (int i = 0; i < 4; ++i) xf[i] = a0[i] + a1[i] + a2[i];

    // ---------------- Phase 2: Picard layers ----------------
    // LDS offsets (loop-invariant). byte(r,c) = r*256 + ((2c)^((r&7)<<4))
    const int swz = (l15 & 7) << 4;
    int offA[4];
    #pragma unroll
    for (int ks = 0; ks < 4; ++ks)
        offA[ks] = l15 * 256 + ((64 * ks + 16 * lq) ^ swz);
    const int offWr = l15 * 256 + ((32 * w + 8 * lq) ^ swz);

    char* zhB = (char*)&zhS[0][0];
    char* zlB = (char*)&zlS[0][0];

    int curFinal = 0;
    for (int l = 0; l < L; ++l) {
        // layer weights -> registers (A-frag: row = colA, k contiguous)
        bf16x8 whf[4], wlf[4];
        {
            const unsigned short* wbh = &Wbh[((long)l * U + colA) * U];
            const unsigned short* wbl = &Wbl[((long)l * U + colA) * U];
            #pragma unroll
            for (int ks = 0; ks < 4; ++ks) {
                const int k = ks * 32 + lq * 8;
                whf[ks] = *(const bf16x8*)&wbh[k];
                wlf[ks] = *(const bf16x8*)&wbl[k];
            }
        }

        // z0 = tanh(x) -> buffer 0 (vectorized hi/lo writes)
        {
            uint2 hh, ll;
            #pragma unroll
            for (int i = 0; i < 4; ++i) { zr[i] = tanh_fast(xf[i]); }
            hh.x = pack2(zr[0], zr[1]); hh.y = pack2(zr[2], zr[3]);
            ll.x = pack2(lo_of(zr[0]), lo_of(zr[1]));
            ll.y = pack2(lo_of(zr[2]), lo_of(zr[3]));
            *(uint2*)(zhB + offWr) = hh;
            *(uint2*)(zlB + offWr) = ll;
        }
        __syncthreads();

        int cur = 0;
        for (int it = 0; it < 48; ++it) {
            const bool chk = ((it & 3) == 0) && (it != 0);
            float g = 1e30f;
            if (chk) {   // consensus from it-1's write; overlaps z reads
                float4 q0 = *(const float4*)&red[0];
                float4 q1 = *(const float4*)&red[4];
                g = fmaxf(fmaxf(fmaxf(q0.x, q0.y), fmaxf(q0.z, q0.w)),
                          fmaxf(fmaxf(q1.x, q1.y), fmaxf(q1.z, q1.w)));
            }
            bf16x8 zhf[4], zlf[4];
            #pragma unroll
            for (int ks = 0; ks < 4; ++ks) {
                zhf[ks] = *(const bf16x8*)(zhB + cur * 4096 + offA[ks]);
                zlf[ks] = *(const bf16x8*)(zlB + cur * 4096 + offA[ks]);
            }
            if (chk && g < 1e-5f) break;

            // 6 independent accumulator chains (depth 2 each)
            f32x4 b0a = {xf[0], xf[1], xf[2], xf[3]};
            f32x4 b0b = {0.f, 0.f, 0.f, 0.f};
            f32x4 b1a = b0b, b1b = b0b, b2a = b0b, b2b = b0b;
            b0a = MFMA(whf[0], zhf[0], b0a);
            b1a = MFMA(whf[0], zlf[0], b1a);
            b2a = MFMA(wlf[0], zhf[0], b2a);
            b0b = MFMA(whf[2], zhf[2], b0b);
            b1b = MFMA(whf[2], zlf[2], b1b);
            b2b = MFMA(wlf[2], zhf[2], b2b);
            b0a = MFMA(whf[1], zhf[1], b0a);
            b1a = MFMA(whf[1], zlf[1], b1a);
            b2a = MFMA(wlf[1], zhf[1], b2a);
            b0b = MFMA(whf[3], zhf[3], b0b);
            b1b = MFMA(whf[3], zlf[3], b1b);
            b2b = MFMA(wlf[3], zhf[3], b2b);

            const int nxt = cur ^ 1;
            float dmax = 0.f;
            #pragma unroll
            for (int i = 0; i < 4; ++i) {
                float t = tanh_fast(b0a[i] + b0b[i] + b1a[i] + b1b[i]
                                  + b2a[i] + b2b[i]);
                dmax = fmaxf(dmax, fabsf(t - zr[i]));
                zr[i] = t;
            }
            uint2 hh, ll;
            hh.x = pack2(zr[0], zr[1]); hh.y = pack2(zr[2], zr[3]);
            ll.x = pack2(lo_of(zr[0]), lo_of(zr[1]));
            ll.y = pack2(lo_of(zr[2]), lo_of(zr[3]));
            *(uint2*)(zhB + nxt * 4096 + offWr) = hh;
            *(uint2*)(zlB + nxt * 4096 + offWr) = ll;

            if ((it & 3) == 3) {       // produce consensus for it+1
                #pragma unroll
                for (int off = 32; off > 0; off >>= 1)
                    dmax = fmaxf(dmax, __shfl_xor(dmax, off));
                if (lane == 0) red[w] = dmax;
            }
            __syncthreads();
            cur = nxt;
        }
        curFinal = cur;
        #pragma unroll
        for (int i = 0; i < 4; ++i) xf[i] = zr[i];   // next layer input
    }

    // ---------------- Phase 3: output GEMM + softmax ----------------
    const char* zhF = zhB + curFinal * 4096;
    const char* zlF = zlB + curFinal * 4096;
    #pragma unroll
    for (int rr2 = 0; rr2 < 2; ++rr2) {
        const int rrow = 2 * w + rr2;
        const int o1 = rrow * 256 + ((lane * 2) ^ ((rrow & 7) << 4));
        const int o2 = rrow * 256 + (((lane + 64) * 2) ^ ((rrow & 7) << 4));
        const float zv0 = fromhi(*(const unsigned short*)(zhF + o1))
                        + fromhi(*(const unsigned short*)(zlF + o1));
        const float zv1 = fromhi(*(const unsigned short*)(zhF + o2))
                        + fromhi(*(const unsigned short*)(zlF + o2));
        float e[10];
        float m = -1e30f;
        #pragma unroll
        for (int o = 0; o < 10; ++o) {
            float p = zv0 * Wo[o * U + lane] + zv1 * Wo[o * U + 64 + lane];
            #pragma unroll
            for (int off = 32; off > 0; off >>= 1)
                p += __shfl_xor(p, off);
            p += bo[o];
            e[o] = p;
            m = fmaxf(m, p);
        }
        float s = 0.f;
        #pragma unroll
        for (int o = 0; o < 10; ++o) {
            e[o] = __expf(e[o] - m);
            s += e[o];
        }
        const float inv = 1.0f / s;
        float v = 0.f;
        #pragma unroll
        for (int o = 0; o < 10; ++o)
            if (lane == o) v = e[o] * inv;
        if (lane < 10) Out[(long)(r0 + rrow) * 10 + lane] = v;
    }
}

// ---------------------------------------------------------------------------
extern "C" void kernel_launch(void* const* d_in, const int* in_sizes, int n_in,
                              void* d_out, int out_size, void* d_ws, size_t ws_size,
                              hipStream_t stream) {
    const float* x  = (const float*)d_in[0];   // [B,784]
    const float* Wi = (const float*)d_in[1];   // [128,784]
    const float* bi = (const float*)d_in[2];   // [128]
    const float* Wb = (const float*)d_in[3];   // [L,128,128]
    const float* Wo = (const float*)d_in[4];   // [10,128]
    const float* bo = (const float*)d_in[5];   // [10]
    float* out = (float*)d_out;

    const int DIN = 784;
    const int B   = in_sizes[0] / DIN;             // 2048
    const int L   = in_sizes[3] / (U * U);         // 2

    const long nX  = (long)B * DIN;
    const long nWi = (long)U * DIN;
    const long nWb = (long)L * U * U;

    unsigned short* Xh  = (unsigned short*)d_ws;
    unsigned short* Xl  = Xh  + nX;
    unsigned short* Wih = Xl  + nX;
    unsigned short* Wil = Wih + nWi;
    unsigned short* WbhP= Wil + nWi;
    unsigned short* WblP= WbhP + nWb;

    const int n4X  = (int)(nX  / 4);
    const int n4Wi = (int)(nWi / 4);
    const int n4Wb = (int)(nWb / 4);
    const int tot4 = n4X + n4Wi + n4Wb;

    k_split<<<(tot4 + 255) / 256, 256, 0, stream>>>(
        x, Wi, Wb, Xh, Xl, Wih, Wil, WbhP, WblP, n4X, n4Wi, n4Wb);

    k_all<<<B / 16, 512, 0, stream>>>(
        Xh, Xl, Wih, Wil, WbhP, WblP, bi, Wo, bo, out, L);
}